// Round 8
// baseline (6019.611 us; speedup 1.0000x reference)
//
#include <hip/hip_runtime.h>
#include <stdint.h>
#include <math.h>

typedef __attribute__((ext_vector_type(8))) short bf16x8;
typedef __attribute__((ext_vector_type(4))) float f32x4;
typedef __attribute__((ext_vector_type(4))) unsigned int u32x4;

#define BATCH 4
#define T_M 32
#define DE 128
#define T_W 2560
#define NWG 56        /* wav-rnn WGs; 4 waves each; wave owns 4 units; 56*4*4 = 896 */

__device__ __forceinline__ float b2f(unsigned short h) {
  return __uint_as_float(((unsigned int)h) << 16);
}
__device__ __forceinline__ unsigned short f2b(float f) {
  unsigned int u = __float_as_uint(f);
  u = u + 0x7fffu + ((u >> 16) & 1u);   // RNE
  return (unsigned short)(u >> 16);
}
__device__ __forceinline__ float blo(unsigned int u){ return __uint_as_float(u << 16); }
__device__ __forceinline__ float bhi(unsigned int u){ return __uint_as_float(u & 0xffff0000u); }
__device__ __forceinline__ float sigm(float x){
  return __builtin_amdgcn_rcpf(1.f + __expf(-x));
}
__device__ __forceinline__ float tanh_fast(float x){
  float x2 = fminf(fmaxf(x + x, -30.f), 30.f);
  return 1.f - 2.f * __builtin_amdgcn_rcpf(__expf(x2) + 1.f);
}
__device__ __forceinline__ float gelu_exact(float x){ return 0.5f * x * (1.f + erff(x * 0.70710678118654752f)); }

// ---------------- fp32 -> bf16 cast ----------------
__global__ __launch_bounds__(256) void k_cast(const float* __restrict__ src,
                                              unsigned short* __restrict__ dst, int n)
{
  int i = blockIdx.x * 256 + threadIdx.x;
  if (i < n) dst[i] = f2b(src[i]);
}

// ---------------- pre-swizzle Whh into per-(G,kc) MFMA A-fragments ----------------
// G (224 groups of 4 units). out[(((G*28+kc)*4+quad)*16 + r16)*8 + j];
// r16<12: row=(r16>>2)*896 + G*4 + (r16&3), col = kc*32 + quad*8 + j; rows 12..15 zero.
__global__ __launch_bounds__(256) void k_prep_whh(const float* __restrict__ whh,
                                                  unsigned short* __restrict__ out)
{
  int idx = blockIdx.x * 256 + threadIdx.x;
  if (idx >= 224 * 28 * 512) return;
  int j    = idx & 7;
  int r16  = (idx >> 3) & 15;
  int quad = (idx >> 7) & 3;
  int kc   = (idx >> 9) % 28;
  int G    = (idx >> 9) / 28;
  unsigned short val = 0;
  if (r16 < 12) {
    int row = (r16 >> 2) * 896 + G * 4 + (r16 & 3);
    int col = kc * 32 + quad * 8 + j;
    val = f2b(whh[(size_t)row * 896 + col]);
  }
  out[idx] = val;
}

// ---------------- encoder: input projections gi = in @ Wih^T + bih ----------------
__global__ __launch_bounds__(384) void k_gi_enc(
    const float* __restrict__ in, const float* __restrict__ Wih,
    const float* __restrict__ bih, float* __restrict__ out, int K)
{
  __shared__ float in_s[256];
  int tb = blockIdx.x;
  for (int i = threadIdx.x; i < K; i += 384) in_s[i] = in[tb * K + i];
  __syncthreads();
  int row = threadIdx.x;
  float acc = bih[row];
  const float* wr = Wih + row * K;
  for (int k = 0; k < K; ++k) acc += in_s[k] * wr[k];
  out[tb * 384 + row] = acc;
}

// ---------------- encoder: sequential scan, one WG per direction ----------------
__global__ __launch_bounds__(512) void k_scan_enc(
    const float* __restrict__ gi_f, const float* __restrict__ gi_b,
    const float* __restrict__ whh_f, const float* __restrict__ bhh_f,
    const float* __restrict__ whh_b, const float* __restrict__ bhh_b,
    float* __restrict__ c_out)   // (32,4,256)
{
  const int dir = blockIdx.x, tid = threadIdx.x;
  const float* gi  = dir ? gi_b  : gi_f;
  const float* whh = dir ? whh_b : whh_f;
  const float* bhh = dir ? bhh_b : bhh_f;
  __shared__ unsigned short h_s[BATCH][DE + 8];
  __shared__ float gh_s[384][4];
  __shared__ float bhh_s[384];
  for (int i = tid; i < 384; i += 512) bhh_s[i] = bhh[i];
  for (int i = tid; i < BATCH * (DE + 8); i += 512) ((unsigned short*)h_s)[i] = 0;
  __syncthreads();
  for (int s = 0; s < T_M; ++s) {
    int t = dir ? (T_M - 1 - s) : s;
    #pragma unroll
    for (int k3 = 0; k3 < 3; ++k3) {
      int d = tid + 512 * k3;
      int row = d >> 2, b = d & 3;
      const float* wr = whh + row * DE;
      float acc = 0.f;
      for (int j = 0; j < DE; j += 8) {
        float4 w0 = *(const float4*)(wr + j);
        float4 w1 = *(const float4*)(wr + j + 4);
        uint4  hv = *(const uint4*)&h_s[b][j];
        acc += w0.x * blo(hv.x) + w0.y * bhi(hv.x) + w0.z * blo(hv.y) + w0.w * bhi(hv.y);
        acc += w1.x * blo(hv.z) + w1.y * bhi(hv.z) + w1.z * blo(hv.w) + w1.w * bhi(hv.w);
      }
      gh_s[row][b] = acc + bhh_s[row];
    }
    __syncthreads();
    {
      int u = tid >> 2, b = tid & 3;
      const float* git = gi + (t * BATCH + b) * 384;
      float r = sigm(git[u] + gh_s[u][b]);
      float z = sigm(git[DE + u] + gh_s[DE + u][b]);
      float n = tanh_fast(git[2 * DE + u] + r * gh_s[2 * DE + u][b]);
      float hold = b2f(h_s[b][u]);
      float hnew = (1.f - z) * n + z * hold;
      c_out[(t * BATCH + b) * 256 + dir * DE + u] = hnew;
      h_s[b][u] = f2b(hnew);
    }
    __syncthreads();
  }
}

// ---------------- MFMA GEMM: C(MxN) = act(A(bf16 MxK) @ B(bf16 NxK)^T + bias) -------
// swz=1: write bf16 into wav-GRU packed gi layout [t][G][gate][batch][unit] (96B blocks)
// afuse=1: A is synthesized on the fly from Eb/c1b/y (wav-GRU input, K=512)
__global__ __launch_bounds__(256) void k_mgemm(
    const unsigned short* __restrict__ A, const unsigned short* __restrict__ B,
    const float* __restrict__ bias, void* __restrict__ C,
    int M, int N, int K, int act, int c_bf16, int swz, int afuse,
    const unsigned short* __restrict__ Eb, const unsigned short* __restrict__ c1b,
    const float* __restrict__ yw)
{
  __shared__ unsigned short As[128][40];
  __shared__ unsigned short Bs[128][40];
  const int tid = threadIdx.x;
  const int m0 = blockIdx.x * 128, n0 = blockIdx.y * 128;
  const int lane = tid & 63, wave = tid >> 6;
  const int wy = wave >> 1, wx = wave & 1;
  const int row16 = lane & 15, quad = lane >> 4;
  const int sr = tid >> 1, sc = (tid & 1) * 16;
  // fused-A row sources (constant per thread)
  const unsigned short* arow0 = nullptr;
  const unsigned short* arow1 = nullptr;
  if (afuse) {
    int row = m0 + sr, tt = row >> 2, b = row & 3;
    float w = (tt == 0) ? 0.f : yw[(tt - 1) * 4 + b];
    int q = (int)floorf((w + 1.f) * 128.f);
    q = q < 0 ? 0 : (q > 255 ? 255 : q);
    arow0 = Eb + q * 256;
    arow1 = c1b + ((tt / 80) * 4 + b) * 256;
  }
  f32x4 acc[4][4] = {};
  for (int kt = 0; kt < K; kt += 32) {
    uint4 av, av2;
    if (afuse) {
      int kk = kt + sc;
      const unsigned short* src = (kk < 256) ? (arow0 + kk) : (arow1 + kk - 256);
      av  = *(const uint4*)src;
      av2 = *(const uint4*)(src + 8);
    } else {
      av  = *(const uint4*)(A + (size_t)(m0 + sr) * K + kt + sc);
      av2 = *(const uint4*)(A + (size_t)(m0 + sr) * K + kt + sc + 8);
    }
    uint4 bv  = *(const uint4*)(B + (size_t)(n0 + sr) * K + kt + sc);
    uint4 bv2 = *(const uint4*)(B + (size_t)(n0 + sr) * K + kt + sc + 8);
    __syncthreads();
    *(uint4*)&As[sr][sc] = av; *(uint4*)&As[sr][sc + 8] = av2;
    *(uint4*)&Bs[sr][sc] = bv; *(uint4*)&Bs[sr][sc + 8] = bv2;
    __syncthreads();
    bf16x8 af[4], bf[4];
    #pragma unroll
    for (int i = 0; i < 4; ++i) af[i] = *(const bf16x8*)&As[wy * 64 + i * 16 + row16][quad * 8];
    #pragma unroll
    for (int j = 0; j < 4; ++j) bf[j] = *(const bf16x8*)&Bs[wx * 64 + j * 16 + row16][quad * 8];
    #pragma unroll
    for (int i = 0; i < 4; ++i)
      #pragma unroll
      for (int j = 0; j < 4; ++j)
        acc[i][j] = __builtin_amdgcn_mfma_f32_16x16x32_bf16(af[i], bf[j], acc[i][j], 0, 0, 0);
  }
  #pragma unroll
  for (int i = 0; i < 4; ++i) {
    #pragma unroll
    for (int j = 0; j < 4; ++j) {
      int col = n0 + wx * 64 + j * 16 + row16;
      float bs = bias[col];
      #pragma unroll
      for (int r = 0; r < 4; ++r) {
        int row = m0 + wy * 64 + i * 16 + quad * 4 + r;
        float v = acc[i][j][r] + bs;
        if (act) v = gelu_exact(v);
        if (swz) {
          int t = row >> 2, b = row & 3;
          int g = col / 896, rem = col - g * 896;
          int G = rem >> 2, u = rem & 3;
          ((unsigned short*)C)[(size_t)(t * 224 + G) * 48 + g * 16 + b * 4 + u] = f2b(v);
        } else if (c_bf16) {
          ((unsigned short*)C)[(size_t)row * N + col] = f2b(v);
        } else {
          ((float*)C)[(size_t)row * N + col] = v;
        }
      }
    }
  }
}

// ---------------- wav GRU: 56 WGs x 4 waves; wave owns G (4 units) ------------------
// LLC protocol (sc0 sc1 packet stores/loads, tag-in-16B-packet, double buffer).
// 4 waves/CU halves the per-CU ds_read_b128 serialization vs 8 waves/CU.
__global__ __launch_bounds__(256, 1) void k_wav_rnn(
    const unsigned short* __restrict__ whh_p,  // swizzled (224,28,4,16,8) bf16
    const float* __restrict__ bhh,             // (2688,)
    const unsigned short* __restrict__ gp_,    // packed gi (2560,224,3,4,4) bf16
    unsigned int* __restrict__ hslots,         // 2*896 packets of 16B, zeroed
    unsigned int* __restrict__ O32)            // (10240,448) dwords of bf16 pairs
{
  const int wg = blockIdx.x, tid = threadIdx.x;
  const int lane = tid & 63, wave = tid >> 6;
  const int G = wg * 4 + wave;                 // global 4-unit group

  __shared__ unsigned short h_lds[2][4][912];  // h(t) double buffer, stride 1824B
  __shared__ float phh[4][3][4][4];            // [wave][gate][batch][unit]

  const int r16 = lane & 15, quad = lane >> 4, bb = lane & 3;
  const int fu = (lane >> 2) & 3, fb = lane & 3;   // finalize mapping (lanes 0-15 real)

  // ---- Whh fragments -> VGPRs (28 x bf16x8 = 112 VGPRs), coalesced 16B/lane ----
  bf16x8 wf[28];
  {
    const bf16x8* W8 = (const bf16x8*)whh_p + (size_t)G * 28 * 64;
    #pragma unroll
    for (int kc = 0; kc < 28; ++kc)
      wf[kc] = W8[(kc * 4 + quad) * 16 + r16];
  }

  // ---- per-lane bias + recurrent state ----
  const float br_ = bhh[G * 4 + fu];
  const float bz_ = bhh[896 + G * 4 + fu];
  const float bn_ = bhh[1792 + G * 4 + fu];
  float hprev = 0.f;
  const unsigned short* gl0 = gp_ + (size_t)G * 48 + fb * 4 + fu;
  unsigned short cr = gl0[0], cz = gl0[16], cn = gl0[32];   // gi(0), raw bf16 bits

  // ---- poll slice: thread covers packets tid, tid+256, tid+512, (tid+768 | dup) ----
  const int p0 = tid, p1 = tid + 256, p2 = tid + 512;
  const int p3 = (tid < 128) ? tid + 768 : tid;    // dup of own p0 when out of range
  const int pb0 = p0 / 224, pG0 = p0 - pb0 * 224;
  const int pb1 = p1 / 224, pG1 = p1 - pb1 * 224;
  const int pb2 = p2 / 224, pG2 = p2 - pb2 * 224;
  const int pb3 = p3 / 224, pG3 = p3 - pb3 * 224;

  const unsigned long long base0 = (unsigned long long)hslots;
  const unsigned long long base1 = base0 + 14336ull;

  for (int t = 0; t < T_W; ++t) {
    // ---- poll my 4 packets (tags == t) ----
    const unsigned long long hb = (t & 1) ? base1 : base0;
    unsigned long long a0 = hb + ((unsigned long long)p0 << 4);
    unsigned long long a1 = hb + ((unsigned long long)p1 << 4);
    unsigned long long a2 = hb + ((unsigned long long)p2 << 4);
    unsigned long long a3 = hb + ((unsigned long long)p3 << 4);
    u32x4 s0, s1, s2, s3;
    const unsigned int tg = (unsigned int)t;
    for (;;) {
      asm volatile(
        "global_load_dwordx4 %0, %4, off sc0 sc1\n"
        "global_load_dwordx4 %1, %5, off sc0 sc1\n"
        "global_load_dwordx4 %2, %6, off sc0 sc1\n"
        "global_load_dwordx4 %3, %7, off sc0 sc1\n"
        "s_waitcnt vmcnt(0)"
        : "=&v"(s0), "=&v"(s1), "=&v"(s2), "=&v"(s3)
        : "v"(a0), "v"(a1), "v"(a2), "v"(a3)
        : "memory");
      unsigned int bad = (s0.z ^ tg) | (s1.z ^ tg) | (s2.z ^ tg) | (s3.z ^ tg);
      if (!__any(bad != 0)) break;
      __builtin_amdgcn_s_sleep(1);   // cut spin power; adds ~64cyc to retry only
    }

    // ---- issue gi(t+1) loads now (raw bf16 bits; consumed at next finalize) ----
    int tn = (t + 1 < T_W) ? (t + 1) : t;
    const unsigned short* gp = gp_ + (size_t)tn * 10752 + G * 48 + fb * 4 + fu;
    unsigned short nr_ = gp[0], nz_ = gp[16], nn_ = gp[32];

    // ---- scatter h(t) into LDS buffer t&1 ----
    *(uint2*)&h_lds[t & 1][pb0][pG0 * 4] = make_uint2(s0.x, s0.y);
    *(uint2*)&h_lds[t & 1][pb1][pG1 * 4] = make_uint2(s1.x, s1.y);
    *(uint2*)&h_lds[t & 1][pb2][pG2 * 4] = make_uint2(s2.x, s2.y);
    *(uint2*)&h_lds[t & 1][pb3][pG3 * 4] = make_uint2(s3.x, s3.y);
    __syncthreads();   // single barrier: h(t) fully in LDS

    // ---- 28 MFMAs, 4 interleaved accumulator chains ----
    f32x4 ac0 = {}, ac1 = {}, ac2 = {}, ac3 = {};
    #pragma unroll
    for (int kc = 0; kc < 28; kc += 4) {
      bf16x8 h0 = *(const bf16x8*)&h_lds[t & 1][bb][(kc + 0) * 32 + quad * 8];
      bf16x8 h1 = *(const bf16x8*)&h_lds[t & 1][bb][(kc + 1) * 32 + quad * 8];
      bf16x8 h2 = *(const bf16x8*)&h_lds[t & 1][bb][(kc + 2) * 32 + quad * 8];
      bf16x8 h3 = *(const bf16x8*)&h_lds[t & 1][bb][(kc + 3) * 32 + quad * 8];
      ac0 = __builtin_amdgcn_mfma_f32_16x16x32_bf16(wf[kc + 0], h0, ac0, 0, 0, 0);
      ac1 = __builtin_amdgcn_mfma_f32_16x16x32_bf16(wf[kc + 1], h1, ac1, 0, 0, 0);
      ac2 = __builtin_amdgcn_mfma_f32_16x16x32_bf16(wf[kc + 2], h2, ac2, 0, 0, 0);
      ac3 = __builtin_amdgcn_mfma_f32_16x16x32_bf16(wf[kc + 3], h3, ac3, 0, 0, 0);
    }
    f32x4 ac;
    ac[0] = ac0[0] + ac1[0] + ac2[0] + ac3[0];
    ac[1] = ac0[1] + ac1[1] + ac2[1] + ac3[1];
    ac[2] = ac0[2] + ac1[2] + ac2[2] + ac3[2];
    ac[3] = ac0[3] + ac1[3] + ac2[3] + ac3[3];

    // ---- in-wave transpose via LDS: D[row=quad*4+reg][col=r16] -> phh[v][g][b][u] ----
    if (r16 < 4 && quad < 3)
      *(f32x4*)&phh[wave][quad][r16][0] = ac;
    asm volatile("s_waitcnt lgkmcnt(0)" ::: "memory");   // same-wave DS in-order

    // ---- finalize my 16 h values (lanes 0-15; others duplicate harmlessly) ----
    float pr = phh[wave][0][fb][fu];
    float pz = phh[wave][1][fb][fu];
    float pn = phh[wave][2][fb][fu];
    float r = sigm(b2f(cr) + br_ + pr);
    float z = sigm(b2f(cz) + bz_ + pz);
    float n = tanh_fast(b2f(cn) + bn_ + r * pn);
    float h = (1.f - z) * n + z * hprev;
    hprev = h;
    unsigned int hu = f2b(h);
    cr = nr_; cz = nz_; cn = nn_;

    // ---- publish: lanes 0-3 own packet (batch b = lane) ----
    int b = lane & 3;
    unsigned int u0v = (unsigned int)__shfl((int)hu, 0 + b);
    unsigned int u1v = (unsigned int)__shfl((int)hu, 4 + b);
    unsigned int u2v = (unsigned int)__shfl((int)hu, 8 + b);
    unsigned int u3v = (unsigned int)__shfl((int)hu, 12 + b);
    if (lane < 4) {
      u32x4 pkt;
      pkt.x = (u0v & 0xffffu) | (u1v << 16);
      pkt.y = (u2v & 0xffffu) | (u3v << 16);
      pkt.z = (unsigned int)(t + 1);
      pkt.w = 0u;
      unsigned long long sa = (((t + 1) & 1) ? base1 : base0)
                            + (unsigned long long)((b * 224 + G) << 4);
      asm volatile("global_store_dwordx4 %0, %1, off sc0 sc1"
                   :: "v"(sa), "v"(pkt) : "memory");
      *(uint2*)(O32 + (size_t)(t * 4 + b) * 448 + G * 2) = make_uint2(pkt.x, pkt.y);
    }
  }
}

// ---------------- NLL ----------------
__global__ __launch_bounds__(256) void k_nll(
    const float* __restrict__ logits, const float* __restrict__ y,
    float* __restrict__ acc)
{
  int wid = threadIdx.x >> 6, lane = threadIdx.x & 63;
  int row = blockIdx.x * 4 + wid;
  const float* lr = logits + (size_t)row * 256;
  float v0 = lr[lane], v1 = lr[lane + 64], v2 = lr[lane + 128], v3 = lr[lane + 192];
  float mx = fmaxf(fmaxf(v0, v1), fmaxf(v2, v3));
  for (int off = 32; off > 0; off >>= 1) mx = fmaxf(mx, __shfl_xor(mx, off));
  float se = __expf(v0 - mx) + __expf(v1 - mx) + __expf(v2 - mx) + __expf(v3 - mx);
  for (int off = 32; off > 0; off >>= 1) se += __shfl_xor(se, off);
  if (lane == 0) {
    float w = y[row];
    int q = (int)floorf((w + 1.f) * 128.f);
    q = q < 0 ? 0 : (q > 255 ? 255 : q);
    float contrib = (logf(se) + mx) - lr[q];
    atomicAdd(acc, contrib);
  }
}

__global__ void k_final(const float* __restrict__ acc, float* __restrict__ out) {
  out[0] = acc[0] * (1.f / 10240.f);
}

// ---------------- host ----------------
extern "C" void kernel_launch(void* const* d_in, const int* in_sizes, int n_in,
                              void* d_out, int out_size, void* d_ws, size_t ws_size,
                              hipStream_t stream)
{
  const float* x       = (const float*)d_in[0];
  const float* y       = (const float*)d_in[1];
  const float* m0f_Wih = (const float*)d_in[2];
  const float* m0f_Whh = (const float*)d_in[3];
  const float* m0f_bih = (const float*)d_in[4];
  const float* m0f_bhh = (const float*)d_in[5];
  const float* m0b_Wih = (const float*)d_in[6];
  const float* m0b_Whh = (const float*)d_in[7];
  const float* m0b_bih = (const float*)d_in[8];
  const float* m0b_bhh = (const float*)d_in[9];
  const float* m1f_Wih = (const float*)d_in[10];
  const float* m1f_Whh = (const float*)d_in[11];
  const float* m1f_bih = (const float*)d_in[12];
  const float* m1f_bhh = (const float*)d_in[13];
  const float* m1b_Wih = (const float*)d_in[14];
  const float* m1b_Whh = (const float*)d_in[15];
  const float* m1b_bih = (const float*)d_in[16];
  const float* m1b_bhh = (const float*)d_in[17];
  const float* w_Wih   = (const float*)d_in[18];
  const float* w_Whh   = (const float*)d_in[19];
  const float* w_bih   = (const float*)d_in[20];
  const float* w_bhh   = (const float*)d_in[21];
  const float* Wp      = (const float*)d_in[22];
  const float* bp      = (const float*)d_in[23];
  const float* E       = (const float*)d_in[24];
  const float* Wd      = (const float*)d_in[25];
  const float* bd      = (const float*)d_in[26];

  char* ws = (char*)d_ws;
  size_t off = 0;
  auto alloc = [&](size_t bytes) -> void* {
    void* p = ws + off;
    off += (bytes + 255) & ~(size_t)255;
    return p;
  };
  // misc (zeroed each launch): nll acc + h packet buffers
  float*        nacc   = (float*)alloc(64);
  unsigned int* hslots = (unsigned int*)alloc(2 * 896 * 16);
  size_t misc_bytes = off;

  float* c0   = (float*)alloc((size_t)32 * 4 * 256 * 4);
  float* c1   = (float*)alloc((size_t)32 * 4 * 256 * 4);
  float* gi0f = (float*)alloc((size_t)32 * 4 * 384 * 4);
  float* gi0b = (float*)alloc((size_t)32 * 4 * 384 * 4);
  float* gi1f = (float*)alloc((size_t)32 * 4 * 384 * 4);
  float* gi1b = (float*)alloc((size_t)32 * 4 * 384 * 4);
  unsigned short* Eb    = (unsigned short*)alloc((size_t)256 * 256 * 2);
  unsigned short* c1b   = (unsigned short*)alloc((size_t)32 * 4 * 256 * 2);
  unsigned short* gpack = (unsigned short*)alloc((size_t)2560 * 224 * 48 * 2);
  unsigned int*   O32   = (unsigned int*)alloc((size_t)10240 * 448 * 4);
  unsigned short* O2    = (unsigned short*)alloc((size_t)10240 * 512 * 2);
  float*          LG    = (float*)alloc((size_t)10240 * 256 * 4);
  unsigned short* Wih_b = (unsigned short*)alloc((size_t)2688 * 512 * 2);
  unsigned short* Whh_p = (unsigned short*)alloc((size_t)224 * 28 * 512 * 2);
  unsigned short* Wp_b  = (unsigned short*)alloc((size_t)512 * 896 * 2);
  unsigned short* Wd_b  = (unsigned short*)alloc((size_t)256 * 512 * 2);

  hipMemsetAsync(d_ws, 0, misc_bytes, stream);

  // weight preprocessing
  k_cast<<<(2688 * 512 + 255) / 256, 256, 0, stream>>>(w_Wih, Wih_b, 2688 * 512);
  k_cast<<<(512 * 896 + 255) / 256, 256, 0, stream>>>(Wp, Wp_b, 512 * 896);
  k_cast<<<(256 * 512 + 255) / 256, 256, 0, stream>>>(Wd, Wd_b, 256 * 512);
  k_cast<<<(256 * 256 + 255) / 256, 256, 0, stream>>>(E, Eb, 256 * 256);
  k_prep_whh<<<(224 * 28 * 512 + 255) / 256, 256, 0, stream>>>(w_Whh, Whh_p);

  // encoder
  k_gi_enc<<<128, 384, 0, stream>>>(x, m0f_Wih, m0f_bih, gi0f, 80);
  k_gi_enc<<<128, 384, 0, stream>>>(x, m0b_Wih, m0b_bih, gi0b, 80);
  k_scan_enc<<<2, 512, 0, stream>>>(gi0f, gi0b, m0f_Whh, m0f_bhh, m0b_Whh, m0b_bhh, c0);
  k_gi_enc<<<128, 384, 0, stream>>>(c0, m1f_Wih, m1f_bih, gi1f, 256);
  k_gi_enc<<<128, 384, 0, stream>>>(c0, m1b_Wih, m1b_bih, gi1b, 256);
  k_scan_enc<<<2, 512, 0, stream>>>(gi1f, gi1b, m1f_Whh, m1f_bhh, m1b_Whh, m1b_bhh, c1);
  k_cast<<<(32 * 4 * 256 + 255) / 256, 256, 0, stream>>>(c1, c1b, 32 * 4 * 256);

  // gi GEMM: A fused from Eb/c1b/y, output written packed (includes bih)
  k_mgemm<<<dim3(80, 21), 256, 0, stream>>>(nullptr, Wih_b, w_bih, (void*)gpack,
                                            10240, 2688, 512, 0, 1, 1, 1, Eb, c1b, y);

  // recurrent wav GRU (persistent, tag-based LLC sync; 56 WGs, 4 waves each)
  k_wav_rnn<<<NWG, 256, 0, stream>>>(Whh_p, w_bhh, gpack, hslots, O32);

  // head
  k_mgemm<<<dim3(80, 4), 256, 0, stream>>>((const unsigned short*)O32, Wp_b, bp,
                                           (void*)O2, 10240, 512, 896, 1, 1, 0, 0,
                                           nullptr, nullptr, nullptr);
  k_mgemm<<<dim3(80, 2), 256, 0, stream>>>(O2, Wd_b, bd, (void*)LG,
                                           10240, 256, 512, 0, 0, 0, 0,
                                           nullptr, nullptr, nullptr);
  k_nll<<<2560, 256, 0, stream>>>(LG, y, nacc);
  k_final<<<1, 1, 0, stream>>>(nacc, (float*)d_out);
}

// Round 9
// 5764.942 us; speedup vs baseline: 1.0442x; 1.0442x over previous
//
#include <hip/hip_runtime.h>
#include <stdint.h>
#include <math.h>

typedef __attribute__((ext_vector_type(8))) short bf16x8;
typedef __attribute__((ext_vector_type(4))) float f32x4;
typedef __attribute__((ext_vector_type(4))) unsigned int u32x4;

#define BATCH 4
#define T_M 32
#define DE 128
#define T_W 2560
#define NWG 56        /* wav-rnn WGs; 4 waves each; wave owns 4 units; 56*4*4 = 896 */

__device__ __forceinline__ float b2f(unsigned short h) {
  return __uint_as_float(((unsigned int)h) << 16);
}
__device__ __forceinline__ unsigned short f2b(float f) {
  unsigned int u = __float_as_uint(f);
  u = u + 0x7fffu + ((u >> 16) & 1u);   // RNE
  return (unsigned short)(u >> 16);
}
__device__ __forceinline__ float blo(unsigned int u){ return __uint_as_float(u << 16); }
__device__ __forceinline__ float bhi(unsigned int u){ return __uint_as_float(u & 0xffff0000u); }
__device__ __forceinline__ float sigm(float x){
  return __builtin_amdgcn_rcpf(1.f + __expf(-x));
}
__device__ __forceinline__ float tanh_fast(float x){
  float x2 = fminf(fmaxf(x + x, -30.f), 30.f);
  return 1.f - 2.f * __builtin_amdgcn_rcpf(__expf(x2) + 1.f);
}
__device__ __forceinline__ float gelu_exact(float x){ return 0.5f * x * (1.f + erff(x * 0.70710678118654752f)); }

// ---------------- fused preprocessing: 4 bf16 casts + Whh swizzle ----------------
// Whh swizzle: G (224 groups of 4 units). out[(((G*28+kc)*4+quad)*16 + r16)*8 + j];
// r16<12: row=(r16>>2)*896 + G*4 + (r16&3), col = kc*32 + quad*8 + j; rows 12..15 zero.
__global__ __launch_bounds__(256) void k_prep(
    const float* __restrict__ wih, const float* __restrict__ wp,
    const float* __restrict__ wd, const float* __restrict__ e,
    const float* __restrict__ whh,
    unsigned short* __restrict__ wih_b, unsigned short* __restrict__ wp_b,
    unsigned short* __restrict__ wd_b, unsigned short* __restrict__ eb,
    unsigned short* __restrict__ whh_p)
{
  int idx = blockIdx.x * 256 + threadIdx.x;
  const int N0 = 2688 * 512, N1 = 512 * 896, N2 = 256 * 512, N3 = 256 * 256;
  if (idx < N0) { wih_b[idx] = f2b(wih[idx]); return; }
  idx -= N0;
  if (idx < N1) { wp_b[idx] = f2b(wp[idx]); return; }
  idx -= N1;
  if (idx < N2) { wd_b[idx] = f2b(wd[idx]); return; }
  idx -= N2;
  if (idx < N3) { eb[idx] = f2b(e[idx]); return; }
  idx -= N3;
  if (idx >= 224 * 28 * 512) return;
  int j    = idx & 7;
  int r16  = (idx >> 3) & 15;
  int quad = (idx >> 7) & 3;
  int kc   = (idx >> 9) % 28;
  int G    = (idx >> 9) / 28;
  unsigned short val = 0;
  if (r16 < 12) {
    int row = (r16 >> 2) * 896 + G * 4 + (r16 & 3);
    int col = kc * 32 + quad * 8 + j;
    val = f2b(whh[(size_t)row * 896 + col]);
  }
  whh_p[idx] = val;
}

// ---------------- encoder: input projections gi = in @ Wih^T + bih (float4) ---------
__global__ __launch_bounds__(384) void k_gi_enc(
    const float* __restrict__ in, const float* __restrict__ Wih,
    const float* __restrict__ bih, float* __restrict__ out, int K)
{
  __shared__ float in_s[256];
  int tb = blockIdx.x;
  for (int i = threadIdx.x; i < K; i += 384) in_s[i] = in[tb * K + i];
  __syncthreads();
  int row = threadIdx.x;
  float acc = bih[row];
  const float* wr = Wih + row * K;
  for (int k = 0; k < K; k += 4) {
    float4 w = *(const float4*)(wr + k);
    float4 v = *(const float4*)(in_s + k);
    acc += w.x * v.x + w.y * v.y + w.z * v.z + w.w * v.w;
  }
  out[tb * 384 + row] = acc;
}

// ---------------- encoder: sequential scan, one WG per direction ----------------
// cb != nullptr: also emit bf16 copy of c_out (for the fused wav-GEMM A operand)
__global__ __launch_bounds__(512) void k_scan_enc(
    const float* __restrict__ gi_f, const float* __restrict__ gi_b,
    const float* __restrict__ whh_f, const float* __restrict__ bhh_f,
    const float* __restrict__ whh_b, const float* __restrict__ bhh_b,
    float* __restrict__ c_out, unsigned short* __restrict__ cb)   // (32,4,256)
{
  const int dir = blockIdx.x, tid = threadIdx.x;
  const float* gi  = dir ? gi_b  : gi_f;
  const float* whh = dir ? whh_b : whh_f;
  const float* bhh = dir ? bhh_b : bhh_f;
  __shared__ unsigned short h_s[BATCH][DE + 8];
  __shared__ float gh_s[384][4];
  __shared__ float bhh_s[384];
  for (int i = tid; i < 384; i += 512) bhh_s[i] = bhh[i];
  for (int i = tid; i < BATCH * (DE + 8); i += 512) ((unsigned short*)h_s)[i] = 0;
  __syncthreads();
  for (int s = 0; s < T_M; ++s) {
    int t = dir ? (T_M - 1 - s) : s;
    #pragma unroll
    for (int k3 = 0; k3 < 3; ++k3) {
      int d = tid + 512 * k3;
      int row = d >> 2, b = d & 3;
      const float* wr = whh + row * DE;
      float acc = 0.f;
      for (int j = 0; j < DE; j += 8) {
        float4 w0 = *(const float4*)(wr + j);
        float4 w1 = *(const float4*)(wr + j + 4);
        uint4  hv = *(const uint4*)&h_s[b][j];
        acc += w0.x * blo(hv.x) + w0.y * bhi(hv.x) + w0.z * blo(hv.y) + w0.w * bhi(hv.y);
        acc += w1.x * blo(hv.z) + w1.y * bhi(hv.z) + w1.z * blo(hv.w) + w1.w * bhi(hv.w);
      }
      gh_s[row][b] = acc + bhh_s[row];
    }
    __syncthreads();
    {
      int u = tid >> 2, b = tid & 3;
      const float* git = gi + (t * BATCH + b) * 384;
      float r = sigm(git[u] + gh_s[u][b]);
      float z = sigm(git[DE + u] + gh_s[DE + u][b]);
      float n = tanh_fast(git[2 * DE + u] + r * gh_s[2 * DE + u][b]);
      float hold = b2f(h_s[b][u]);
      float hnew = (1.f - z) * n + z * hold;
      int oi = (t * BATCH + b) * 256 + dir * DE + u;
      c_out[oi] = hnew;
      if (cb) cb[oi] = f2b(hnew);
      h_s[b][u] = f2b(hnew);
    }
    __syncthreads();
  }
}

// ---------------- MFMA GEMM: C(MxN) = act(A(bf16 MxK) @ B(bf16 NxK)^T + bias) -------
// swz=1: write bf16 into wav-GRU packed gi layout [t][G][gate][batch][unit] (96B blocks)
// afuse=1: A is synthesized on the fly from Eb/c1b/y (wav-GRU input, K=512)
__global__ __launch_bounds__(256) void k_mgemm(
    const unsigned short* __restrict__ A, const unsigned short* __restrict__ B,
    const float* __restrict__ bias, void* __restrict__ C,
    int M, int N, int K, int act, int c_bf16, int swz, int afuse,
    const unsigned short* __restrict__ Eb, const unsigned short* __restrict__ c1b,
    const float* __restrict__ yw)
{
  __shared__ unsigned short As[128][40];
  __shared__ unsigned short Bs[128][40];
  const int tid = threadIdx.x;
  const int m0 = blockIdx.x * 128, n0 = blockIdx.y * 128;
  const int lane = tid & 63, wave = tid >> 6;
  const int wy = wave >> 1, wx = wave & 1;
  const int row16 = lane & 15, quad = lane >> 4;
  const int sr = tid >> 1, sc = (tid & 1) * 16;
  // fused-A row sources (constant per thread)
  const unsigned short* arow0 = nullptr;
  const unsigned short* arow1 = nullptr;
  if (afuse) {
    int row = m0 + sr, tt = row >> 2, b = row & 3;
    float w = (tt == 0) ? 0.f : yw[(tt - 1) * 4 + b];
    int q = (int)floorf((w + 1.f) * 128.f);
    q = q < 0 ? 0 : (q > 255 ? 255 : q);
    arow0 = Eb + q * 256;
    arow1 = c1b + ((tt / 80) * 4 + b) * 256;
  }
  f32x4 acc[4][4] = {};
  for (int kt = 0; kt < K; kt += 32) {
    uint4 av, av2;
    if (afuse) {
      int kk = kt + sc;
      const unsigned short* src = (kk < 256) ? (arow0 + kk) : (arow1 + kk - 256);
      av  = *(const uint4*)src;
      av2 = *(const uint4*)(src + 8);
    } else {
      av  = *(const uint4*)(A + (size_t)(m0 + sr) * K + kt + sc);
      av2 = *(const uint4*)(A + (size_t)(m0 + sr) * K + kt + sc + 8);
    }
    uint4 bv  = *(const uint4*)(B + (size_t)(n0 + sr) * K + kt + sc);
    uint4 bv2 = *(const uint4*)(B + (size_t)(n0 + sr) * K + kt + sc + 8);
    __syncthreads();
    *(uint4*)&As[sr][sc] = av; *(uint4*)&As[sr][sc + 8] = av2;
    *(uint4*)&Bs[sr][sc] = bv; *(uint4*)&Bs[sr][sc + 8] = bv2;
    __syncthreads();
    bf16x8 af[4], bf[4];
    #pragma unroll
    for (int i = 0; i < 4; ++i) af[i] = *(const bf16x8*)&As[wy * 64 + i * 16 + row16][quad * 8];
    #pragma unroll
    for (int j = 0; j < 4; ++j) bf[j] = *(const bf16x8*)&Bs[wx * 64 + j * 16 + row16][quad * 8];
    #pragma unroll
    for (int i = 0; i < 4; ++i)
      #pragma unroll
      for (int j = 0; j < 4; ++j)
        acc[i][j] = __builtin_amdgcn_mfma_f32_16x16x32_bf16(af[i], bf[j], acc[i][j], 0, 0, 0);
  }
  #pragma unroll
  for (int i = 0; i < 4; ++i) {
    #pragma unroll
    for (int j = 0; j < 4; ++j) {
      int col = n0 + wx * 64 + j * 16 + row16;
      float bs = bias[col];
      #pragma unroll
      for (int r = 0; r < 4; ++r) {
        int row = m0 + wy * 64 + i * 16 + quad * 4 + r;
        float v = acc[i][j][r] + bs;
        if (act) v = gelu_exact(v);
        if (swz) {
          int t = row >> 2, b = row & 3;
          int g = col / 896, rem = col - g * 896;
          int G = rem >> 2, u = rem & 3;
          ((unsigned short*)C)[(size_t)(t * 224 + G) * 48 + g * 16 + b * 4 + u] = f2b(v);
        } else if (c_bf16) {
          ((unsigned short*)C)[(size_t)row * N + col] = f2b(v);
        } else {
          ((float*)C)[(size_t)row * N + col] = v;
        }
      }
    }
  }
}

// ---------------- wav GRU: 56 WGs x 4 waves; wave owns G (4 units) ------------------
// LLC protocol (sc0 sc1 packet stores/loads, tag-in-16B-packet, double buffer).
__global__ __launch_bounds__(256, 1) void k_wav_rnn(
    const unsigned short* __restrict__ whh_p,  // swizzled (224,28,4,16,8) bf16
    const float* __restrict__ bhh,             // (2688,)
    const unsigned short* __restrict__ gp_,    // packed gi (2560,224,3,4,4) bf16
    unsigned int* __restrict__ hslots,         // 2*896 packets of 16B, zeroed
    unsigned int* __restrict__ O32)            // (10240,448) dwords of bf16 pairs
{
  const int wg = blockIdx.x, tid = threadIdx.x;
  const int lane = tid & 63, wave = tid >> 6;
  const int G = wg * 4 + wave;                 // global 4-unit group

  __shared__ unsigned short h_lds[2][4][912];  // h(t) double buffer, stride 1824B
  __shared__ float phh[4][3][4][4];            // [wave][gate][batch][unit]

  const int r16 = lane & 15, quad = lane >> 4, bb = lane & 3;
  const int fu = (lane >> 2) & 3, fb = lane & 3;   // finalize mapping (lanes 0-15 real)

  // ---- Whh fragments -> VGPRs (28 x bf16x8 = 112 VGPRs), coalesced 16B/lane ----
  bf16x8 wf[28];
  {
    const bf16x8* W8 = (const bf16x8*)whh_p + (size_t)G * 28 * 64;
    #pragma unroll
    for (int kc = 0; kc < 28; ++kc)
      wf[kc] = W8[(kc * 4 + quad) * 16 + r16];
  }

  // ---- per-lane bias + recurrent state ----
  const float br_ = bhh[G * 4 + fu];
  const float bz_ = bhh[896 + G * 4 + fu];
  const float bn_ = bhh[1792 + G * 4 + fu];
  float hprev = 0.f;
  const unsigned short* gl0 = gp_ + (size_t)G * 48 + fb * 4 + fu;
  unsigned short cr = gl0[0], cz = gl0[16], cn = gl0[32];   // gi(0), raw bf16 bits

  // ---- poll slice: thread covers packets tid, tid+256, tid+512, (tid+768 | dup) ----
  const int p0 = tid, p1 = tid + 256, p2 = tid + 512;
  const int p3 = (tid < 128) ? tid + 768 : tid;    // dup of own p0 when out of range
  const int pb0 = p0 / 224, pG0 = p0 - pb0 * 224;
  const int pb1 = p1 / 224, pG1 = p1 - pb1 * 224;
  const int pb2 = p2 / 224, pG2 = p2 - pb2 * 224;
  const int pb3 = p3 / 224, pG3 = p3 - pb3 * 224;

  const unsigned long long base0 = (unsigned long long)hslots;
  const unsigned long long base1 = base0 + 14336ull;

  for (int t = 0; t < T_W; ++t) {
    // ---- poll my 4 packets (tags == t) ----
    const unsigned long long hb = (t & 1) ? base1 : base0;
    unsigned long long a0 = hb + ((unsigned long long)p0 << 4);
    unsigned long long a1 = hb + ((unsigned long long)p1 << 4);
    unsigned long long a2 = hb + ((unsigned long long)p2 << 4);
    unsigned long long a3 = hb + ((unsigned long long)p3 << 4);
    u32x4 s0, s1, s2, s3;
    const unsigned int tg = (unsigned int)t;
    for (;;) {
      asm volatile(
        "global_load_dwordx4 %0, %4, off sc0 sc1\n"
        "global_load_dwordx4 %1, %5, off sc0 sc1\n"
        "global_load_dwordx4 %2, %6, off sc0 sc1\n"
        "global_load_dwordx4 %3, %7, off sc0 sc1\n"
        "s_waitcnt vmcnt(0)"
        : "=&v"(s0), "=&v"(s1), "=&v"(s2), "=&v"(s3)
        : "v"(a0), "v"(a1), "v"(a2), "v"(a3)
        : "memory");
      unsigned int bad = (s0.z ^ tg) | (s1.z ^ tg) | (s2.z ^ tg) | (s3.z ^ tg);
      if (!__any(bad != 0)) break;
    }

    // ---- issue gi(t+1) loads now (raw bf16 bits; consumed at next finalize) ----
    int tn = (t + 1 < T_W) ? (t + 1) : t;
    const unsigned short* gp = gp_ + (size_t)tn * 10752 + G * 48 + fb * 4 + fu;
    unsigned short nr_ = gp[0], nz_ = gp[16], nn_ = gp[32];

    // ---- scatter h(t) into LDS buffer t&1 ----
    *(uint2*)&h_lds[t & 1][pb0][pG0 * 4] = make_uint2(s0.x, s0.y);
    *(uint2*)&h_lds[t & 1][pb1][pG1 * 4] = make_uint2(s1.x, s1.y);
    *(uint2*)&h_lds[t & 1][pb2][pG2 * 4] = make_uint2(s2.x, s2.y);
    *(uint2*)&h_lds[t & 1][pb3][pG3 * 4] = make_uint2(s3.x, s3.y);
    __syncthreads();   // single barrier: h(t) fully in LDS

    // ---- 28 MFMAs, 4 interleaved accumulator chains ----
    f32x4 ac0 = {}, ac1 = {}, ac2 = {}, ac3 = {};
    #pragma unroll
    for (int kc = 0; kc < 28; kc += 4) {
      bf16x8 h0 = *(const bf16x8*)&h_lds[t & 1][bb][(kc + 0) * 32 + quad * 8];
      bf16x8 h1 = *(const bf16x8*)&h_lds[t & 1][bb][(kc + 1) * 32 + quad * 8];
      bf16x8 h2 = *(const bf16x8*)&h_lds[t & 1][bb][(kc + 2) * 32 + quad * 8];
      bf16x8 h3 = *(const bf16x8*)&h_lds[t & 1][bb][(kc + 3) * 32 + quad * 8];
      ac0 = __builtin_amdgcn_mfma_f32_16x16x32_bf16(wf[kc + 0], h0, ac0, 0, 0, 0);
      ac1 = __builtin_amdgcn_mfma_f32_16x16x32_bf16(wf[kc + 1], h1, ac1, 0, 0, 0);
      ac2 = __builtin_amdgcn_mfma_f32_16x16x32_bf16(wf[kc + 2], h2, ac2, 0, 0, 0);
      ac3 = __builtin_amdgcn_mfma_f32_16x16x32_bf16(wf[kc + 3], h3, ac3, 0, 0, 0);
    }
    f32x4 ac;
    ac[0] = ac0[0] + ac1[0] + ac2[0] + ac3[0];
    ac[1] = ac0[1] + ac1[1] + ac2[1] + ac3[1];
    ac[2] = ac0[2] + ac1[2] + ac2[2] + ac3[2];
    ac[3] = ac0[3] + ac1[3] + ac2[3] + ac3[3];

    // ---- in-wave transpose via LDS: D[row=quad*4+reg][col=r16] -> phh[v][g][b][u] ----
    if (r16 < 4 && quad < 3)
      *(f32x4*)&phh[wave][quad][r16][0] = ac;
    asm volatile("s_waitcnt lgkmcnt(0)" ::: "memory");   // same-wave DS in-order

    // ---- finalize my 16 h values (lanes 0-15; others duplicate harmlessly) ----
    float pr = phh[wave][0][fb][fu];
    float pz = phh[wave][1][fb][fu];
    float pn = phh[wave][2][fb][fu];
    float r = sigm(b2f(cr) + br_ + pr);
    float z = sigm(b2f(cz) + bz_ + pz);
    float n = tanh_fast(b2f(cn) + bn_ + r * pn);
    float h = (1.f - z) * n + z * hprev;
    hprev = h;
    unsigned int hu = f2b(h);
    cr = nr_; cz = nz_; cn = nn_;

    // ---- publish: lanes 0-3 own packet (batch b = lane) ----
    int b = lane & 3;
    unsigned int u0v = (unsigned int)__shfl((int)hu, 0 + b);
    unsigned int u1v = (unsigned int)__shfl((int)hu, 4 + b);
    unsigned int u2v = (unsigned int)__shfl((int)hu, 8 + b);
    unsigned int u3v = (unsigned int)__shfl((int)hu, 12 + b);
    if (lane < 4) {
      u32x4 pkt;
      pkt.x = (u0v & 0xffffu) | (u1v << 16);
      pkt.y = (u2v & 0xffffu) | (u3v << 16);
      pkt.z = (unsigned int)(t + 1);
      pkt.w = 0u;
      unsigned long long sa = (((t + 1) & 1) ? base1 : base0)
                            + (unsigned long long)((b * 224 + G) << 4);
      asm volatile("global_store_dwordx4 %0, %1, off sc0 sc1"
                   :: "v"(sa), "v"(pkt) : "memory");
      *(uint2*)(O32 + (size_t)(t * 4 + b) * 448 + G * 2) = make_uint2(pkt.x, pkt.y);
    }
  }
}

// ---------------- NLL: per-block reduction, NO atomics ----------------
__global__ __launch_bounds__(256) void k_nll(
    const float* __restrict__ logits, const float* __restrict__ y,
    float* __restrict__ partials)
{
  __shared__ float ps[4];
  int wid = threadIdx.x >> 6, lane = threadIdx.x & 63;
  int row = blockIdx.x * 4 + wid;
  const float* lr = logits + (size_t)row * 256;
  float v0 = lr[lane], v1 = lr[lane + 64], v2 = lr[lane + 128], v3 = lr[lane + 192];
  float mx = fmaxf(fmaxf(v0, v1), fmaxf(v2, v3));
  for (int off = 32; off > 0; off >>= 1) mx = fmaxf(mx, __shfl_xor(mx, off));
  float se = __expf(v0 - mx) + __expf(v1 - mx) + __expf(v2 - mx) + __expf(v3 - mx);
  for (int off = 32; off > 0; off >>= 1) se += __shfl_xor(se, off);
  if (lane == 0) {
    float w = y[row];
    int q = (int)floorf((w + 1.f) * 128.f);
    q = q < 0 ? 0 : (q > 255 ? 255 : q);
    ps[wid] = (logf(se) + mx) - lr[q];
  }
  __syncthreads();
  if (threadIdx.x == 0) partials[blockIdx.x] = ps[0] + ps[1] + ps[2] + ps[3];
}

__global__ __launch_bounds__(256) void k_final(const float* __restrict__ partials,
                                               float* __restrict__ out)
{
  __shared__ float s[4];
  int tid = threadIdx.x;
  float a = 0.f;
  for (int i = tid; i < 2560; i += 256) a += partials[i];
  for (int off = 32; off > 0; off >>= 1) a += __shfl_xor(a, off);
  if ((tid & 63) == 0) s[tid >> 6] = a;
  __syncthreads();
  if (tid == 0) out[0] = (s[0] + s[1] + s[2] + s[3]) * (1.f / 10240.f);
}

// ---------------- host ----------------
extern "C" void kernel_launch(void* const* d_in, const int* in_sizes, int n_in,
                              void* d_out, int out_size, void* d_ws, size_t ws_size,
                              hipStream_t stream)
{
  const float* x       = (const float*)d_in[0];
  const float* y       = (const float*)d_in[1];
  const float* m0f_Wih = (const float*)d_in[2];
  const float* m0f_Whh = (const float*)d_in[3];
  const float* m0f_bih = (const float*)d_in[4];
  const float* m0f_bhh = (const float*)d_in[5];
  const float* m0b_Wih = (const float*)d_in[6];
  const float* m0b_Whh = (const float*)d_in[7];
  const float* m0b_bih = (const float*)d_in[8];
  const float* m0b_bhh = (const float*)d_in[9];
  const float* m1f_Wih = (const float*)d_in[10];
  const float* m1f_Whh = (const float*)d_in[11];
  const float* m1f_bih = (const float*)d_in[12];
  const float* m1f_bhh = (const float*)d_in[13];
  const float* m1b_Wih = (const float*)d_in[14];
  const float* m1b_Whh = (const float*)d_in[15];
  const float* m1b_bih = (const float*)d_in[16];
  const float* m1b_bhh = (const float*)d_in[17];
  const float* w_Wih   = (const float*)d_in[18];
  const float* w_Whh   = (const float*)d_in[19];
  const float* w_bih   = (const float*)d_in[20];
  const float* w_bhh   = (const float*)d_in[21];
  const float* Wp      = (const float*)d_in[22];
  const float* bp      = (const float*)d_in[23];
  const float* E       = (const float*)d_in[24];
  const float* Wd      = (const float*)d_in[25];
  const float* bd      = (const float*)d_in[26];

  char* ws = (char*)d_ws;
  size_t off = 0;
  auto alloc = [&](size_t bytes) -> void* {
    void* p = ws + off;
    off += (bytes + 255) & ~(size_t)255;
    return p;
  };
  // misc (zeroed each launch): h packet buffers
  unsigned int* hslots = (unsigned int*)alloc(2 * 896 * 16);
  size_t misc_bytes = off;

  float* c0   = (float*)alloc((size_t)32 * 4 * 256 * 4);
  float* c1   = (float*)alloc((size_t)32 * 4 * 256 * 4);
  float* gi0f = (float*)alloc((size_t)32 * 4 * 384 * 4);
  float* gi0b = (float*)alloc((size_t)32 * 4 * 384 * 4);
  float* gi1f = (float*)alloc((size_t)32 * 4 * 384 * 4);
  float* gi1b = (float*)alloc((size_t)32 * 4 * 384 * 4);
  unsigned short* Eb    = (unsigned short*)alloc((size_t)256 * 256 * 2);
  unsigned short* c1b   = (unsigned short*)alloc((size_t)32 * 4 * 256 * 2);
  unsigned short* gpack = (unsigned short*)alloc((size_t)2560 * 224 * 48 * 2);
  unsigned int*   O32   = (unsigned int*)alloc((size_t)10240 * 448 * 4);
  unsigned short* O2    = (unsigned short*)alloc((size_t)10240 * 512 * 2);
  float*          LG    = (float*)alloc((size_t)10240 * 256 * 4);
  float*          PT    = (float*)alloc((size_t)2560 * 4);
  unsigned short* Wih_b = (unsigned short*)alloc((size_t)2688 * 512 * 2);
  unsigned short* Whh_p = (unsigned short*)alloc((size_t)224 * 28 * 512 * 2);
  unsigned short* Wp_b  = (unsigned short*)alloc((size_t)512 * 896 * 2);
  unsigned short* Wd_b  = (unsigned short*)alloc((size_t)256 * 512 * 2);

  hipMemsetAsync(d_ws, 0, misc_bytes, stream);

  // fused weight preprocessing (4 casts + Whh swizzle)
  {
    int total = 2688 * 512 + 512 * 896 + 256 * 512 + 256 * 256 + 224 * 28 * 512;
    k_prep<<<(total + 255) / 256, 256, 0, stream>>>(
        w_Wih, Wp, Wd, E, w_Whh, Wih_b, Wp_b, Wd_b, Eb, Whh_p);
  }

  // encoder
  k_gi_enc<<<128, 384, 0, stream>>>(x, m0f_Wih, m0f_bih, gi0f, 80);
  k_gi_enc<<<128, 384, 0, stream>>>(x, m0b_Wih, m0b_bih, gi0b, 80);
  k_scan_enc<<<2, 512, 0, stream>>>(gi0f, gi0b, m0f_Whh, m0f_bhh, m0b_Whh, m0b_bhh,
                                    c0, nullptr);
  k_gi_enc<<<128, 384, 0, stream>>>(c0, m1f_Wih, m1f_bih, gi1f, 256);
  k_gi_enc<<<128, 384, 0, stream>>>(c0, m1b_Wih, m1b_bih, gi1b, 256);
  k_scan_enc<<<2, 512, 0, stream>>>(gi1f, gi1b, m1f_Whh, m1f_bhh, m1b_Whh, m1b_bhh,
                                    c1, c1b);

  // gi GEMM: A fused from Eb/c1b/y, output written packed (includes bih)
  k_mgemm<<<dim3(80, 21), 256, 0, stream>>>(nullptr, Wih_b, w_bih, (void*)gpack,
                                            10240, 2688, 512, 0, 1, 1, 1, Eb, c1b, y);

  // recurrent wav GRU (persistent, tag-based LLC sync; 56 WGs, 4 waves each)
  k_wav_rnn<<<NWG, 256, 0, stream>>>(Whh_p, w_bhh, gpack, hslots, O32);

  // head
  k_mgemm<<<dim3(80, 4), 256, 0, stream>>>((const unsigned short*)O32, Wp_b, bp,
                                           (void*)O2, 10240, 512, 896, 1, 1, 0, 0,
                                           nullptr, nullptr, nullptr);
  k_mgemm<<<dim3(80, 2), 256, 0, stream>>>(O2, Wd_b, bd, (void*)LG,
                                           10240, 256, 512, 0, 0, 0, 0,
                                           nullptr, nullptr, nullptr);
  k_nll<<<2560, 256, 0, stream>>>(LG, y, PT);
  k_final<<<1, 256, 0, stream>>>(PT, (float*)d_out);
}